// Round 9
// baseline (201.880 us; speedup 1.0000x reference)
//
#include <hip/hip_runtime.h>
#include <hip/hip_bf16.h>

// Problem: B=512, N_SLOTS=128, IN=2048, MEM=64, OUT=2048.
// Dtype self-detection per wave (ballot on x's bit patterns); fp32-world
// confirmed R4-R8, bf16 world also handled.
// Pipeline (3 dispatches): k_pack (bf16-pack x->Abf, Wo^T->Bt, proj weights
// ->Wt, biases) -> k_projfused (px in LDS + scores/softmax/recalls/mem-update;
// recalls -> Abf tail) -> k_gemm (barrier-free wave-tiled MFMA, 4-stage
// register pipeline).
// d_out = [output (512*2048) | new_memory (512*128*64)], input dtype.

#define NB    512
#define NSLOT 128
#define DIN   2048
#define DMEM  64
#define DOUT  2048
#define PXW   130              // 64 (q) + 1 (forget) + 65 (remember)
#define KT    (DIN + 2 * DMEM) // 2176 = GEMM K and packed row stride
#define NK    (KT / 32)        // 68

typedef __hip_bfloat16 bf16;
typedef __attribute__((ext_vector_type(8))) short short8;
typedef __attribute__((ext_vector_type(4))) float f32x4;

template<bool BF16>
__device__ __forceinline__ float ld(const void* p, size_t i) {
  if (BF16) return __bfloat162float(((const bf16*)p)[i]);
  return ((const float*)p)[i];
}
template<bool BF16>
__device__ __forceinline__ void st(void* p, size_t i, float v) {
  if (BF16) ((bf16*)p)[i] = __float2bfloat16(v);
  else      ((float*)p)[i] = v;
}
// f32 -> bf16 bits (RNE); bf16 bits -> f32 (exact).
__device__ __forceinline__ unsigned short f2bu(float f) {
  unsigned int u = __builtin_bit_cast(unsigned int, f);
  u = (u + 0x7FFFu + ((u >> 16) & 1u)) >> 16;
  return (unsigned short)u;
}
__device__ __forceinline__ float bu2f(unsigned short u) {
  unsigned int w = ((unsigned int)u) << 16;
  return __builtin_bit_cast(float, w);
}

// Wave-level dtype detect: sample 64 even uint16 positions of x. bf16 data ->
// sane exponents (~100% of N(0,1)); f32 data -> even positions are mantissa
// low-halves (~16% sane). Deterministic: same addresses every wave/launch.
__device__ __forceinline__ bool detect_bf16(const void* x) {
  const unsigned short* u = (const unsigned short*)x;
  int lane = threadIdx.x & 63;
  unsigned short v = u[lane * 2048];
  int e = (v >> 7) & 0xFF;
  unsigned long long m = __ballot(e >= 100 && e <= 140);
  return __popcll(m) > 32;
}

union U8x16 { uint4 v; unsigned short u[8]; };

// ---------------------------------------------------------------------------
// k_pack: one dispatch, block ranges:
//  [0,1088)   : Bt[n][k] = Wo[k][n] bf16   (34 k-tiles x 32 n-tiles, LDS transpose)
//  [1088,1216): Abf[b][0:2048] = x bf16    (4 rows/block)
//  [1216,1280): Wt[j][k] = proj-weight col j (LDS transpose, 65-col halves)
//  [1280,1288): bias_o[2048] f32
//  [1288]     : bias_px[130] f32
// ---------------------------------------------------------------------------
template<bool BF16>
__device__ void pack_body(
    const void* x, const void* W_ar, const void* W_f, const void* W_r,
    const void* Wo, const void* b_ar, const void* b_f, const void* b_r,
    const void* bo,
    unsigned short* Abf, unsigned short* Bt, unsigned short* Wt,
    float* bias_o, float* bias_px, unsigned short* tile) {
  int t = blockIdx.x, tid = threadIdx.x;
  if (t < 1088) {
    int kt = t % 34, nt = t / 34;
    int k0 = kt * 64, n0 = nt * 64;
    for (int i = tid; i < 64 * 64; i += 256) {
      int kk = i >> 6, nn = i & 63;   // consecutive tid -> consecutive nn (coalesced)
      tile[nn * 66 + kk] = f2bu(ld<BF16>(Wo, (size_t)(k0 + kk) * DOUT + n0 + nn));
    }
    __syncthreads();
    for (int i = tid; i < 64 * 64; i += 256) {
      int nn = i >> 6, kk = i & 63;   // consecutive kk -> coalesced writes
      Bt[(size_t)(n0 + nn) * KT + k0 + kk] = tile[nn * 66 + kk];
    }
  } else if (t < 1216) {
    int bx = t - 1088;
    for (int i = tid; i < 8192; i += 256) {
      int r = bx * 4 + (i >> 11), c = i & 2047;
      Abf[(size_t)r * KT + c] = f2bu(ld<BF16>(x, (size_t)r * DIN + c));
    }
  } else if (t < 1280) {
    int q = t - 1216;
    int k0 = (q >> 1) * 64, j0 = (q & 1) * 65;
    for (int i = tid; i < 64 * 65; i += 256) {
      int kl = i / 65, jl = i % 65;
      int j = j0 + jl, k = k0 + kl;
      float v;
      if (j < 64)       v = ld<BF16>(W_ar, (size_t)k * 64 + j);
      else if (j == 64) v = ld<BF16>(W_f, k);
      else              v = ld<BF16>(W_r, (size_t)k * 65 + (j - 65));
      tile[jl * 66 + kl] = f2bu(v);
    }
    __syncthreads();
    for (int i = tid; i < 65 * 64; i += 256) {
      int jl = i >> 6, kk = i & 63;
      Wt[(size_t)(j0 + jl) * DIN + k0 + kk] = tile[jl * 66 + kk];
    }
  } else if (t < 1288) {
    int c = (t - 1280) * 256 + tid;
    bias_o[c] = ld<BF16>(bo, c);
  } else {
    if (tid < PXW) {
      float v;
      if (tid < 64)       v = ld<BF16>(b_ar, tid);
      else if (tid == 64) v = ld<BF16>(b_f, 0);
      else                v = ld<BF16>(b_r, tid - 65);
      bias_px[tid] = v;
    }
  }
}

__global__ __launch_bounds__(256) void k_pack(
    const void* __restrict__ x, const void* __restrict__ W_ar,
    const void* __restrict__ W_f, const void* __restrict__ W_r,
    const void* __restrict__ Wo, const void* __restrict__ b_ar,
    const void* __restrict__ b_f, const void* __restrict__ b_r,
    const void* __restrict__ bo,
    unsigned short* __restrict__ Abf, unsigned short* __restrict__ Bt,
    unsigned short* __restrict__ Wt, float* __restrict__ bias_o,
    float* __restrict__ bias_px) {
  __shared__ unsigned short tile[65 * 66];
  if (detect_bf16(x))
    pack_body<true >(x, W_ar, W_f, W_r, Wo, b_ar, b_f, b_r, bo, Abf, Bt, Wt, bias_o, bias_px, tile);
  else
    pack_body<false>(x, W_ar, W_f, W_r, Wo, b_ar, b_f, b_r, bo, Abf, Bt, Wt, bias_o, bias_px, tile);
}

// ---------------------------------------------------------------------------
// k_projfused: per-batch block b.
// Phase 1 (dtype-free): xs <- Abf row; px_s[130] = xs @ Wt^T + bias_px (LDS).
// Phase 2: per-slot dots, two LDS-tree softmaxes, recalls -> Abf tail (bf16),
// gated memory update -> d_out (input dtype).
// ---------------------------------------------------------------------------
template<bool BF16>
__device__ void fused_body(
    const void* memory, const void* W_pr, const void* b_pr,
    const void* W_f, const void* W_r,
    unsigned short* Abf, void* dout,
    float* mem_s, float* wrm_s, float* smem) {
  float* wfm_s = smem;            // 64
  float* wpr_s = wfm_s + 64;      // 64
  float* px_s  = wpr_s + 64;      // 130 (written in phase 1)
  float* sa    = px_s + 130;      // 128
  float* sp    = sa + 128;        // 128
  float* ra    = sp + 128;        // 128
  float* rb    = ra + 128;        // 128
  float* forget_s = rb + 128;     // 128
  float* r64_s    = forget_s + 128;

  float* qs    = px_s;            // px[0:64]
  float* pxr_s = px_s + 65;       // px[65:130]

  int b = blockIdx.x, tid = threadIdx.x;
  size_t mb = (size_t)b * (NSLOT * DMEM);
  for (int i = tid; i < NSLOT * DMEM; i += 256)
    mem_s[(i >> 6) * 65 + (i & 63)] = ld<BF16>(memory, mb + i);
  for (int i = tid; i < 64 * 65; i += 256)
    wrm_s[(i / 65) * 68 + (i % 65)] = ld<BF16>(W_r, 2048 * 65 + i);
  if (tid < 64) {
    wfm_s[tid] = ld<BF16>(W_f, 2048 + tid);
    wpr_s[tid] = ld<BF16>(W_pr, tid);
  }
  __syncthreads();   // also makes phase-1 px_s visible

  float pxf = px_s[64];

  if (tid < 128) {
    const float* mr = &mem_s[tid * 65];
    float aa = 0.f, pp = 0.f, ff = 0.f, rr = 0.f;
#pragma unroll 8
    for (int k = 0; k < 64; ++k) {
      float m = mr[k];
      aa += m * qs[k];
      pp += m * wpr_s[k];
      ff += m * wfm_s[k];
      rr += m * wrm_s[k * 68 + 64];
    }
    sa[tid] = aa;
    sp[tid] = pp + ld<BF16>(b_pr, 0);
    forget_s[tid] = 1.1f / (1.f + __expf(-(ff + pxf)));
    r64_s[tid]    = rr + pxr_s[64];
  }
  __syncthreads();

  if (tid < 128) ra[tid] = sa[tid]; else rb[tid - 128] = sp[tid - 128];
  __syncthreads();
  for (int s = 64; s; s >>= 1) {
    if (tid < s) ra[tid] = fmaxf(ra[tid], ra[tid + s]);
    else if (tid >= 128 && tid < 128 + s) rb[tid - 128] = fmaxf(rb[tid - 128], rb[tid - 128 + s]);
    __syncthreads();
  }
  float mxA = ra[0], mxB = rb[0];
  __syncthreads();
  if (tid < 128) { float e = __expf(sa[tid] - mxA); sa[tid] = e; ra[tid] = e; }
  else           { float e = __expf(sp[tid - 128] - mxB); sp[tid - 128] = e; rb[tid - 128] = e; }
  __syncthreads();
  for (int s = 64; s; s >>= 1) {
    if (tid < s) ra[tid] += ra[tid + s];
    else if (tid >= 128 && tid < 128 + s) rb[tid - 128] += rb[tid - 128 + s];
    __syncthreads();
  }
  float invA = 1.f / ra[0], invB = 1.f / rb[0];
  __syncthreads();
  if (tid < 128) sa[tid] *= invA; else sp[tid - 128] *= invB;
  __syncthreads();

  // recalls -> Abf[b][2048 + 0:128] as bf16 (GEMM A tail)
  if (tid < 128) {
    int m = tid & 63;
    const float* w = (tid < 64) ? sa : sp;
    float acc = 0.f;
#pragma unroll 8
    for (int n = 0; n < NSLOT; ++n) acc += mem_s[n * 65 + m] * w[n];
    Abf[(size_t)b * KT + DIN + tid] = f2bu(acc);
  }

  size_t obase = (size_t)NB * DOUT + mb;
  for (int Q = tid; Q < NSLOT * 16; Q += 256) {
    int n = Q >> 4, j0 = (Q & 15) * 4;
    const float* mr = &mem_s[n * 65];
    float r0 = 0.f, r1 = 0.f, r2 = 0.f, r3 = 0.f;
#pragma unroll 8
    for (int k = 0; k < 64; ++k) {
      float mv = mr[k];
      const float* wr = &wrm_s[k * 68 + j0];
      r0 += mv * wr[0]; r1 += mv * wr[1]; r2 += mv * wr[2]; r3 += mv * wr[3];
    }
    float fg = forget_s[n], r64 = r64_s[n];
    size_t o = obase + n * DMEM + j0;
    st<BF16>(dout, o + 0, mr[j0 + 0] * fg + r64 * (r0 + pxr_s[j0 + 0]));
    st<BF16>(dout, o + 1, mr[j0 + 1] * fg + r64 * (r1 + pxr_s[j0 + 1]));
    st<BF16>(dout, o + 2, mr[j0 + 2] * fg + r64 * (r2 + pxr_s[j0 + 2]));
    st<BF16>(dout, o + 3, mr[j0 + 3] * fg + r64 * (r3 + pxr_s[j0 + 3]));
  }
}

__global__ __launch_bounds__(256) void k_projfused(
    const void* __restrict__ x, const void* __restrict__ memory,
    const void* __restrict__ W_pr, const void* __restrict__ b_pr,
    const void* __restrict__ W_f,  const void* __restrict__ W_r,
    unsigned short* __restrict__ Abf,
    const unsigned short* __restrict__ Wt,
    const float* __restrict__ bias_px,
    void* __restrict__ dout) {
  __shared__ float xs[DIN];
  __shared__ float mem_s[NSLOT * 65];
  __shared__ float wrm_s[64 * 68];
  __shared__ float smem[64 * 2 + 130 + 128 * 6];
  float* px_s = smem + 128;

  // ---- phase 1: px (dtype-free, reads packed Abf/Wt) ----
  int b = blockIdx.x, tid = threadIdx.x;
  for (int k = tid; k < DIN; k += 256) xs[k] = bu2f(Abf[(size_t)b * KT + k]);
  __syncthreads();
  int wv = tid >> 6, lane = tid & 63;
  for (int j = wv; j < PXW; j += 4) {
    const unsigned short* wc = Wt + (size_t)j * DIN;
    float acc = 0.f;
#pragma unroll
    for (int i = 0; i < 4; ++i) {
      int k0 = i * 512 + lane * 8;
      U8x16 t; t.v = *(const uint4*)(wc + k0);
      const float4* xp = (const float4*)&xs[k0];
      float4 xa = xp[0], xb = xp[1];
      acc += xa.x * bu2f(t.u[0]) + xa.y * bu2f(t.u[1])
           + xa.z * bu2f(t.u[2]) + xa.w * bu2f(t.u[3])
           + xb.x * bu2f(t.u[4]) + xb.y * bu2f(t.u[5])
           + xb.z * bu2f(t.u[6]) + xb.w * bu2f(t.u[7]);
    }
#pragma unroll
    for (int off = 32; off; off >>= 1) acc += __shfl_xor(acc, off, 64);
    if (lane == 0) px_s[j] = acc + bias_px[j];
  }
  // px_s visibility: first __syncthreads inside fused_body (after staging).

  // ---- phase 2 ----
  if (detect_bf16(x))
    fused_body<true >(memory, W_pr, b_pr, W_f, W_r, Abf, dout, mem_s, wrm_s, smem);
  else
    fused_body<false>(memory, W_pr, b_pr, W_f, W_r, Abf, dout, mem_s, wrm_s, smem);
}

// ---------------------------------------------------------------------------
// k_gemm v3: output = Abf @ Bt^T + bias_o. Barrier-free: 512 blocks x 4
// waves; wave tile 16 rows x 32 cols (the 4 waves of a block share one
// 32-col B tile -> L1 reuse). 4-stage register pipeline, prefetch distance
// 3, #pragma unroll 4 (NK=68 % 4 == 0) so stage indices are static.
// Fragment layouts (verified R5-R8): A/B: m|n=lane&15, k=(lane>>4)*8+j;
// D: col=lane&15, row=(lane>>4)*4+reg.
// ---------------------------------------------------------------------------
template<bool BF16>
__device__ void gemm_body(const unsigned short* Abf, const unsigned short* Bt,
                          const float* bias_o, void* dout) {
  int tid = threadIdx.x;
  int lane = tid & 63, w = tid >> 6;
  int col0 = (blockIdx.x >> 3) * 32;
  int row0 = (blockIdx.x & 7) * 64 + w * 16;
  int lr = lane & 15, lk = (lane >> 4) * 8;

  const unsigned short* Ap  = Abf + (size_t)(row0 + lr) * KT + lk;
  const unsigned short* Bp0 = Bt  + (size_t)(col0 + lr) * KT + lk;
  const unsigned short* Bp1 = Bt  + (size_t)(col0 + 16 + lr) * KT + lk;

  f32x4 acc0 = {}, acc1 = {};
  short8 a[4], b0[4], b1[4];
#pragma unroll
  for (int s = 0; s < 3; ++s) {
    int k = s * 32;
    a[s]  = *(const short8*)(Ap + k);
    b0[s] = *(const short8*)(Bp0 + k);
    b1[s] = *(const short8*)(Bp1 + k);
  }
#pragma unroll 4
  for (int i = 0; i < NK; ++i) {
    int s = i & 3;
    int pf = i + 3;
    if (pf < NK) {
      int ps = pf & 3, k = pf * 32;
      a[ps]  = *(const short8*)(Ap + k);
      b0[ps] = *(const short8*)(Bp0 + k);
      b1[ps] = *(const short8*)(Bp1 + k);
    }
    acc0 = __builtin_amdgcn_mfma_f32_16x16x32_bf16(a[s], b0[s], acc0, 0, 0, 0);
    acc1 = __builtin_amdgcn_mfma_f32_16x16x32_bf16(a[s], b1[s], acc1, 0, 0, 0);
  }

  int rbase = row0 + (lane >> 4) * 4;
  {
    int c = col0 + lr;
    float bias = bias_o[c];
#pragma unroll
    for (int r = 0; r < 4; ++r)
      st<BF16>(dout, (size_t)(rbase + r) * DOUT + c, acc0[r] + bias);
  }
  {
    int c = col0 + 16 + lr;
    float bias = bias_o[c];
#pragma unroll
    for (int r = 0; r < 4; ++r)
      st<BF16>(dout, (size_t)(rbase + r) * DOUT + c, acc1[r] + bias);
  }
}

__global__ __launch_bounds__(256) void k_gemm(
    const void* __restrict__ x,
    const unsigned short* __restrict__ Abf,
    const unsigned short* __restrict__ Bt,
    const float* __restrict__ bias_o, void* __restrict__ dout) {
  if (detect_bf16(x)) gemm_body<true >(Abf, Bt, bias_o, dout);
  else                gemm_body<false>(Abf, Bt, bias_o, dout);
}

// ---------------------------------------------------------------------------
extern "C" void kernel_launch(void* const* d_in, const int* in_sizes, int n_in,
                              void* d_out, int out_size, void* d_ws, size_t ws_size,
                              hipStream_t stream) {
  const void* x    = d_in[0];
  const void* mem  = d_in[1];
  const void* W_ar = d_in[2];
  const void* b_ar = d_in[3];
  const void* W_pr = d_in[4];
  const void* b_pr = d_in[5];
  const void* W_f  = d_in[6];
  const void* b_f  = d_in[7];
  const void* W_r  = d_in[8];
  const void* b_r  = d_in[9];
  const void* W_o  = d_in[10];
  const void* b_o  = d_in[11];

  unsigned short* Abf     = (unsigned short*)d_ws;          // 512*2176
  unsigned short* Bt      = Abf + (size_t)NB * KT;          // 2048*2176
  unsigned short* Wt      = Bt + (size_t)DOUT * KT;         // 130*2048
  float*          bias_o  = (float*)(Wt + PXW * DIN);       // 2048 f32
  float*          bias_px = bias_o + DOUT;                  // 130 f32

  k_pack<<<1289, 256, 0, stream>>>(x, W_ar, W_f, W_r, W_o, b_ar, b_f, b_r, b_o,
                                   Abf, Bt, Wt, bias_o, bias_px);
  k_projfused<<<NB, 256, 0, stream>>>(x, mem, W_pr, b_pr, W_f, W_r,
                                      Abf, Wt, bias_px, d_out);
  k_gemm<<<512, 256, 0, stream>>>(x, Abf, Bt, bias_o, d_out);
}

// Round 10
// 200.554 us; speedup vs baseline: 1.0066x; 1.0066x over previous
//
#include <hip/hip_runtime.h>
#include <hip/hip_bf16.h>

// Problem: B=512, N_SLOTS=128, IN=2048, MEM=64, OUT=2048.
// Dtype self-detection per wave (ballot on x's bit patterns); fp32-world
// confirmed R4-R9, bf16 world also handled.
// Pipeline (3 dispatches): k_pack -> k_projfused (px + MFMA rem/gates +
// softmax/recalls/mem-update) -> k_gemm (barrier-free wave-tiled MFMA).
// d_out = [output (512*2048) | new_memory (512*128*64)], input dtype.

#define NB    512
#define NSLOT 128
#define DIN   2048
#define DMEM  64
#define DOUT  2048
#define PXW   130              // 64 (q) + 1 (forget) + 65 (remember)
#define KT    (DIN + 2 * DMEM) // 2176 = GEMM K and packed row stride
#define NK    (KT / 32)        // 68

typedef __hip_bfloat16 bf16;
typedef __attribute__((ext_vector_type(8))) short short8;
typedef __attribute__((ext_vector_type(4))) float f32x4;

template<bool BF16>
__device__ __forceinline__ float ld(const void* p, size_t i) {
  if (BF16) return __bfloat162float(((const bf16*)p)[i]);
  return ((const float*)p)[i];
}
template<bool BF16>
__device__ __forceinline__ void st(void* p, size_t i, float v) {
  if (BF16) ((bf16*)p)[i] = __float2bfloat16(v);
  else      ((float*)p)[i] = v;
}
__device__ __forceinline__ float ld_rt(bool isbf, const void* p, size_t i) {
  return isbf ? __bfloat162float(((const bf16*)p)[i]) : ((const float*)p)[i];
}
__device__ __forceinline__ void st_rt(bool isbf, void* p, size_t i, float v) {
  if (isbf) ((bf16*)p)[i] = __float2bfloat16(v);
  else      ((float*)p)[i] = v;
}
// f32 -> bf16 bits (RNE); bf16 bits -> f32 (exact).
__device__ __forceinline__ unsigned short f2bu(float f) {
  unsigned int u = __builtin_bit_cast(unsigned int, f);
  u = (u + 0x7FFFu + ((u >> 16) & 1u)) >> 16;
  return (unsigned short)u;
}
__device__ __forceinline__ float bu2f(unsigned short u) {
  unsigned int w = ((unsigned int)u) << 16;
  return __builtin_bit_cast(float, w);
}

// Wave-level dtype detect: sample 64 even uint16 positions of x. bf16 data ->
// sane exponents (~100% of N(0,1)); f32 data -> even positions are mantissa
// low-halves (~16% sane). Deterministic: same addresses every wave/launch.
__device__ __forceinline__ bool detect_bf16(const void* x) {
  const unsigned short* u = (const unsigned short*)x;
  int lane = threadIdx.x & 63;
  unsigned short v = u[lane * 2048];
  int e = (v >> 7) & 0xFF;
  unsigned long long m = __ballot(e >= 100 && e <= 140);
  return __popcll(m) > 32;
}

union U8x16 { uint4 v; unsigned short u[8]; };

// ---------------------------------------------------------------------------
// k_pack: one dispatch, block ranges:
//  [0,1088)   : Bt[n][k] = Wo[k][n] bf16   (34 k-tiles x 32 n-tiles, LDS transpose)
//  [1088,1216): Abf[b][0:2048] = x bf16    (4 rows/block)
//  [1216,1280): Wt[j][k] = proj-weight col j (LDS transpose, 65-col halves)
//  [1280,1288): bias_o[2048] f32
//  [1288]     : bias_px[130] f32
// ---------------------------------------------------------------------------
template<bool BF16>
__device__ void pack_body(
    const void* x, const void* W_ar, const void* W_f, const void* W_r,
    const void* Wo, const void* b_ar, const void* b_f, const void* b_r,
    const void* bo,
    unsigned short* Abf, unsigned short* Bt, unsigned short* Wt,
    float* bias_o, float* bias_px, unsigned short* tile) {
  int t = blockIdx.x, tid = threadIdx.x;
  if (t < 1088) {
    int kt = t % 34, nt = t / 34;
    int k0 = kt * 64, n0 = nt * 64;
    for (int i = tid; i < 64 * 64; i += 256) {
      int kk = i >> 6, nn = i & 63;   // consecutive tid -> consecutive nn (coalesced)
      tile[nn * 66 + kk] = f2bu(ld<BF16>(Wo, (size_t)(k0 + kk) * DOUT + n0 + nn));
    }
    __syncthreads();
    for (int i = tid; i < 64 * 64; i += 256) {
      int nn = i >> 6, kk = i & 63;   // consecutive kk -> coalesced writes
      Bt[(size_t)(n0 + nn) * KT + k0 + kk] = tile[nn * 66 + kk];
    }
  } else if (t < 1216) {
    int bx = t - 1088;
    for (int i = tid; i < 8192; i += 256) {
      int r = bx * 4 + (i >> 11), c = i & 2047;
      Abf[(size_t)r * KT + c] = f2bu(ld<BF16>(x, (size_t)r * DIN + c));
    }
  } else if (t < 1280) {
    int q = t - 1216;
    int k0 = (q >> 1) * 64, j0 = (q & 1) * 65;
    for (int i = tid; i < 64 * 65; i += 256) {
      int kl = i / 65, jl = i % 65;
      int j = j0 + jl, k = k0 + kl;
      float v;
      if (j < 64)       v = ld<BF16>(W_ar, (size_t)k * 64 + j);
      else if (j == 64) v = ld<BF16>(W_f, k);
      else              v = ld<BF16>(W_r, (size_t)k * 65 + (j - 65));
      tile[jl * 66 + kl] = f2bu(v);
    }
    __syncthreads();
    for (int i = tid; i < 65 * 64; i += 256) {
      int jl = i >> 6, kk = i & 63;
      Wt[(size_t)(j0 + jl) * DIN + k0 + kk] = tile[jl * 66 + kk];
    }
  } else if (t < 1288) {
    int c = (t - 1280) * 256 + tid;
    bias_o[c] = ld<BF16>(bo, c);
  } else {
    if (tid < PXW) {
      float v;
      if (tid < 64)       v = ld<BF16>(b_ar, tid);
      else if (tid == 64) v = ld<BF16>(b_f, 0);
      else                v = ld<BF16>(b_r, tid - 65);
      bias_px[tid] = v;
    }
  }
}

__global__ __launch_bounds__(256) void k_pack(
    const void* __restrict__ x, const void* __restrict__ W_ar,
    const void* __restrict__ W_f, const void* __restrict__ W_r,
    const void* __restrict__ Wo, const void* __restrict__ b_ar,
    const void* __restrict__ b_f, const void* __restrict__ b_r,
    const void* __restrict__ bo,
    unsigned short* __restrict__ Abf, unsigned short* __restrict__ Bt,
    unsigned short* __restrict__ Wt, float* __restrict__ bias_o,
    float* __restrict__ bias_px) {
  __shared__ unsigned short tile[65 * 66];
  if (detect_bf16(x))
    pack_body<true >(x, W_ar, W_f, W_r, Wo, b_ar, b_f, b_r, bo, Abf, Bt, Wt, bias_o, bias_px, tile);
  else
    pack_body<false>(x, W_ar, W_f, W_r, Wo, b_ar, b_f, b_r, bo, Abf, Bt, Wt, bias_o, bias_px, tile);
}

// ---------------------------------------------------------------------------
// k_projfused: per-batch block b.
//  stage:  xs (f32 from Abf), memu (mem bf16 [128][72]), w2t ([80][72] bf16:
//          rows 0..64 = W_r mem-part cols, 65 = W_f mem-part, 66 = W_pr,
//          67..79 = 0)
//  phase1: px_s[130] = xs @ Wt^T + bias_px (wave-per-column, shuffle reduce)
//  MFMA:   mem @ w2t^T -> rem cols 0..63 (in-register) + rem64/ff/pp (stash)
//  gates:  sa (scalar q-dot), sp, forget, r64; two LDS-tree softmaxes;
//          recalls -> Abf tail; new_memory from acc regs -> d_out.
// ---------------------------------------------------------------------------
__global__ __launch_bounds__(256) void k_projfused(
    const void* __restrict__ x, const void* __restrict__ memory,
    const void* __restrict__ W_pr, const void* __restrict__ b_pr,
    const void* __restrict__ W_f,  const void* __restrict__ W_r,
    unsigned short* __restrict__ Abf,
    const unsigned short* __restrict__ Wt,
    const float* __restrict__ bias_px,
    void* __restrict__ dout) {
  __shared__ float xs[DIN];
  __shared__ unsigned short memu[NSLOT * 72];
  __shared__ unsigned short w2t[80 * 72];
  __shared__ float px_s[PXW];
  __shared__ float sa[128], sp[128], ra[128], rb[128];
  __shared__ float forget_s[128], r64_s[128];
  __shared__ float st64[128], stf[128], stp[128];

  bool isbf = detect_bf16(x);
  int b = blockIdx.x, tid = threadIdx.x;
  size_t mb = (size_t)b * (NSLOT * DMEM);

  // ---- stage ----
  for (int k = tid; k < DIN; k += 256) xs[k] = bu2f(Abf[(size_t)b * KT + k]);
  for (int i = tid; i < 1024; i += 256) {
    int idx = i * 8, n = idx >> 6, k = idx & 63;
    unsigned short* dst = &memu[n * 72 + k];
    if (isbf) {
      *(uint4*)dst = *(const uint4*)((const unsigned short*)memory + mb + idx);
    } else {
      const float4* q = (const float4*)((const float*)memory + mb + idx);
      float4 fa = q[0], fb = q[1];
      dst[0] = f2bu(fa.x); dst[1] = f2bu(fa.y); dst[2] = f2bu(fa.z); dst[3] = f2bu(fa.w);
      dst[4] = f2bu(fb.x); dst[5] = f2bu(fb.y); dst[6] = f2bu(fb.z); dst[7] = f2bu(fb.w);
    }
  }
  for (int i = tid; i < 80 * 64; i += 256) {
    int kk = i / 80, j = i - kk * 80;
    float v = 0.f;
    if (j < 65)       v = ld_rt(isbf, W_r, (size_t)(2048 + kk) * 65 + j);
    else if (j == 65) v = ld_rt(isbf, W_f, 2048 + kk);
    else if (j == 66) v = ld_rt(isbf, W_pr, kk);
    w2t[j * 72 + kk] = f2bu(v);
  }
  __syncthreads();

  int w = tid >> 6, lane = tid & 63;
  int lr = lane & 15, lkq = (lane >> 4) * 8;

  // ---- phase 1: px ----
  for (int j = w; j < PXW; j += 4) {
    const unsigned short* wc = Wt + (size_t)j * DIN;
    float acc1 = 0.f;
#pragma unroll
    for (int i = 0; i < 4; ++i) {
      int k0 = i * 512 + lane * 8;
      U8x16 t; t.v = *(const uint4*)(wc + k0);
      const float4* xp = (const float4*)&xs[k0];
      float4 xa = xp[0], xb = xp[1];
      acc1 += xa.x * bu2f(t.u[0]) + xa.y * bu2f(t.u[1])
            + xa.z * bu2f(t.u[2]) + xa.w * bu2f(t.u[3])
            + xb.x * bu2f(t.u[4]) + xb.y * bu2f(t.u[5])
            + xb.z * bu2f(t.u[6]) + xb.w * bu2f(t.u[7]);
    }
#pragma unroll
    for (int off = 32; off; off >>= 1) acc1 += __shfl_xor(acc1, off, 64);
    if (lane == 0) px_s[j] = acc1 + bias_px[j];
  }

  // ---- MFMA: mem[128x64] @ w2t^T[64x80]; wave w owns slots w*32..w*32+31 ----
  // Fragment layouts (verified R5-R9): A: m=lane&15, k=(lane>>4)*8+j;
  // B: n=lane&15 (= w2t row), same k; D: col=lane&15, row=(lane>>4)*4+reg.
  f32x4 acc[2][5] = {};
#pragma unroll
  for (int ks = 0; ks < 2; ++ks) {
    int ko = ks * 32 + lkq;
    short8 a0 = *(const short8*)&memu[(w * 32 + lr) * 72 + ko];
    short8 a1 = *(const short8*)&memu[(w * 32 + 16 + lr) * 72 + ko];
#pragma unroll
    for (int nt = 0; nt < 5; ++nt) {
      short8 bb = *(const short8*)&w2t[(nt * 16 + lr) * 72 + ko];
      acc[0][nt] = __builtin_amdgcn_mfma_f32_16x16x32_bf16(a0, bb, acc[0][nt], 0, 0, 0);
      acc[1][nt] = __builtin_amdgcn_mfma_f32_16x16x32_bf16(a1, bb, acc[1][nt], 0, 0, 0);
    }
  }
  // stash cols 64 (rem64 raw), 65 (forget dot), 66 (passive dot)
#pragma unroll
  for (int i = 0; i < 2; ++i) {
    if (lr < 3) {
      float* dstp = (lr == 0) ? st64 : (lr == 1) ? stf : stp;
#pragma unroll
      for (int r = 0; r < 4; ++r) {
        int slot = w * 32 + i * 16 + (lane >> 4) * 4 + r;
        dstp[slot] = acc[i][4][r];
      }
    }
  }
  __syncthreads();   // px_s + stashes visible

  float pxf = px_s[64];
  const float* qs = px_s;
  const float* pxr_s = px_s + 65;

  // ---- gates + active score ----
  if (tid < 128) {
    const unsigned short* mr = &memu[tid * 72];
    float aa = 0.f;
#pragma unroll 8
    for (int k = 0; k < 64; ++k) aa += bu2f(mr[k]) * qs[k];
    sa[tid] = aa;
    sp[tid] = stp[tid] + ld_rt(isbf, b_pr, 0);
    forget_s[tid] = 1.1f / (1.f + __expf(-(stf[tid] + pxf)));
    r64_s[tid]    = st64[tid] + pxr_s[64];
  }
  __syncthreads();

  // ---- two softmaxes over 128 slots via LDS trees ----
  if (tid < 128) ra[tid] = sa[tid]; else rb[tid - 128] = sp[tid - 128];
  __syncthreads();
  for (int s = 64; s; s >>= 1) {
    if (tid < s) ra[tid] = fmaxf(ra[tid], ra[tid + s]);
    else if (tid >= 128 && tid < 128 + s) rb[tid - 128] = fmaxf(rb[tid - 128], rb[tid - 128 + s]);
    __syncthreads();
  }
  float mxA = ra[0], mxB = rb[0];
  __syncthreads();
  if (tid < 128) { float e = __expf(sa[tid] - mxA); sa[tid] = e; ra[tid] = e; }
  else           { float e = __expf(sp[tid - 128] - mxB); sp[tid - 128] = e; rb[tid - 128] = e; }
  __syncthreads();
  for (int s = 64; s; s >>= 1) {
    if (tid < s) ra[tid] += ra[tid + s];
    else if (tid >= 128 && tid < 128 + s) rb[tid - 128] += rb[tid - 128 + s];
    __syncthreads();
  }
  float invA = 1.f / ra[0], invB = 1.f / rb[0];
  __syncthreads();
  if (tid < 128) sa[tid] *= invA; else sp[tid - 128] *= invB;
  __syncthreads();

  // ---- recalls -> Abf[b][2048 + 0:128] (bf16 GEMM A tail) ----
  if (tid < 128) {
    int m = tid & 63;
    const float* wv = (tid < 64) ? sa : sp;
    float accr = 0.f;
#pragma unroll 8
    for (int n = 0; n < NSLOT; ++n) accr += bu2f(memu[n * 72 + m]) * wv[n];
    Abf[(size_t)b * KT + DIN + tid] = f2bu(accr);
  }

  // ---- new_memory from acc registers ----
  size_t obase = (size_t)NB * DOUT + mb;
#pragma unroll
  for (int i = 0; i < 2; ++i) {
#pragma unroll
    for (int nt = 0; nt < 4; ++nt) {
#pragma unroll
      for (int r = 0; r < 4; ++r) {
        int slot = w * 32 + i * 16 + (lane >> 4) * 4 + r;
        int j = nt * 16 + lr;
        float mv = bu2f(memu[slot * 72 + j]);
        float v = mv * forget_s[slot] + r64_s[slot] * (acc[i][nt][r] + pxr_s[j]);
        st_rt(isbf, dout, obase + (size_t)slot * DMEM + j, v);
      }
    }
  }
}

// ---------------------------------------------------------------------------
// k_gemm: output = Abf @ Bt^T + bias_o. Barrier-free: 512 blocks x 4 waves;
// wave tile 16 rows x 32 cols; 4-stage register pipeline, prefetch dist 3.
// ---------------------------------------------------------------------------
template<bool BF16>
__device__ void gemm_body(const unsigned short* Abf, const unsigned short* Bt,
                          const float* bias_o, void* dout) {
  int tid = threadIdx.x;
  int lane = tid & 63, w = tid >> 6;
  int col0 = (blockIdx.x >> 3) * 32;
  int row0 = (blockIdx.x & 7) * 64 + w * 16;
  int lr = lane & 15, lk = (lane >> 4) * 8;

  const unsigned short* Ap  = Abf + (size_t)(row0 + lr) * KT + lk;
  const unsigned short* Bp0 = Bt  + (size_t)(col0 + lr) * KT + lk;
  const unsigned short* Bp1 = Bt  + (size_t)(col0 + 16 + lr) * KT + lk;

  f32x4 acc0 = {}, acc1 = {};
  short8 a[4], b0[4], b1[4];
#pragma unroll
  for (int s = 0; s < 3; ++s) {
    int k = s * 32;
    a[s]  = *(const short8*)(Ap + k);
    b0[s] = *(const short8*)(Bp0 + k);
    b1[s] = *(const short8*)(Bp1 + k);
  }
#pragma unroll 4
  for (int i = 0; i < NK; ++i) {
    int s = i & 3;
    int pf = i + 3;
    if (pf < NK) {
      int ps = pf & 3, k = pf * 32;
      a[ps]  = *(const short8*)(Ap + k);
      b0[ps] = *(const short8*)(Bp0 + k);
      b1[ps] = *(const short8*)(Bp1 + k);
    }
    acc0 = __builtin_amdgcn_mfma_f32_16x16x32_bf16(a[s], b0[s], acc0, 0, 0, 0);
    acc1 = __builtin_amdgcn_mfma_f32_16x16x32_bf16(a[s], b1[s], acc1, 0, 0, 0);
  }

  int rbase = row0 + (lane >> 4) * 4;
  {
    int c = col0 + lr;
    float bias = bias_o[c];
#pragma unroll
    for (int r = 0; r < 4; ++r)
      st<BF16>(dout, (size_t)(rbase + r) * DOUT + c, acc0[r] + bias);
  }
  {
    int c = col0 + 16 + lr;
    float bias = bias_o[c];
#pragma unroll
    for (int r = 0; r < 4; ++r)
      st<BF16>(dout, (size_t)(rbase + r) * DOUT + c, acc1[r] + bias);
  }
}

__global__ __launch_bounds__(256) void k_gemm(
    const void* __restrict__ x,
    const unsigned short* __restrict__ Abf,
    const unsigned short* __restrict__ Bt,
    const float* __restrict__ bias_o, void* __restrict__ dout) {
  if (detect_bf16(x)) gemm_body<true >(Abf, Bt, bias_o, dout);
  else                gemm_body<false>(Abf, Bt, bias_o, dout);
}

// ---------------------------------------------------------------------------
extern "C" void kernel_launch(void* const* d_in, const int* in_sizes, int n_in,
                              void* d_out, int out_size, void* d_ws, size_t ws_size,
                              hipStream_t stream) {
  const void* x    = d_in[0];
  const void* mem  = d_in[1];
  const void* W_ar = d_in[2];
  const void* b_ar = d_in[3];
  const void* W_pr = d_in[4];
  const void* b_pr = d_in[5];
  const void* W_f  = d_in[6];
  const void* b_f  = d_in[7];
  const void* W_r  = d_in[8];
  const void* b_r  = d_in[9];
  const void* W_o  = d_in[10];
  const void* b_o  = d_in[11];

  unsigned short* Abf     = (unsigned short*)d_ws;          // 512*2176
  unsigned short* Bt      = Abf + (size_t)NB * KT;          // 2048*2176
  unsigned short* Wt      = Bt + (size_t)DOUT * KT;         // 130*2048
  float*          bias_o  = (float*)(Wt + PXW * DIN);       // 2048 f32
  float*          bias_px = bias_o + DOUT;                  // 130 f32

  k_pack<<<1289, 256, 0, stream>>>(x, W_ar, W_f, W_r, W_o, b_ar, b_f, b_r, b_o,
                                   Abf, Bt, Wt, bias_o, bias_px);
  k_projfused<<<NB, 256, 0, stream>>>(x, mem, W_pr, b_pr, W_f, W_r,
                                      Abf, Wt, bias_px, d_out);
  k_gemm<<<512, 256, 0, stream>>>(x, Abf, Bt, bias_o, d_out);
}